// Round 2
// baseline (1140.956 us; speedup 1.0000x reference)
//
#include <hip/hip_runtime.h>
#include <hip/hip_bf16.h>

// MultiHeadAttention: B=2, T=2048, D=1024, H=16, DK=64.
// Inputs/outputs FP32 (per reference); internal compute bf16 MFMA + fp32 softmax.
// d_out = (attn_out [B,T,D], weights [B,H,T,T]) concat flat, fp32.
#define B_  2
#define T_  2048
#define D_  1024
#define H_  16
#define DK_ 64
#define M_  (B_*T_)   // 4096 rows for projections

typedef unsigned short u16;
typedef short s8v  __attribute__((ext_vector_type(8)));   // 8 bf16 in 4 VGPRs
typedef float f4v  __attribute__((ext_vector_type(4)));

__device__ inline u16 f2bf(float f) {
    union { float f; unsigned u; } v; v.f = f;
    unsigned u = v.u;
    u += 0x7fffu + ((u >> 16) & 1u);   // RNE
    return (u16)(u >> 16);
}

// ---------------------------------------------------------------------------
// Conversion pre-pass: fp32 -> bf16 into ws. One float4 per thread.
// ---------------------------------------------------------------------------
__global__ __launch_bounds__(256) void cvtA(   // q,k,v inputs (4,194,304 elems each)
    const float* __restrict__ s0, const float* __restrict__ s1, const float* __restrict__ s2,
    u16* __restrict__ dst)
{
    const int seg = blockIdx.y;
    const float* s = (seg == 0) ? s0 : (seg == 1) ? s1 : s2;
    u16* d = dst + (size_t)seg * 4194304;
    size_t i = (size_t)blockIdx.x * 256 + threadIdx.x;   // float4 index, 1,048,576 total
    float4 v = ((const float4*)s)[i];
    ushort4 o;
    o.x = f2bf(v.x); o.y = f2bf(v.y); o.z = f2bf(v.z); o.w = f2bf(v.w);
    ((ushort4*)d)[i] = o;
}

__global__ __launch_bounds__(256) void cvtB(   // W_q,W_k,W_v,W_o (1,048,576 elems each)
    const float* __restrict__ s0, const float* __restrict__ s1,
    const float* __restrict__ s2, const float* __restrict__ s3,
    u16* __restrict__ dst)
{
    const int seg = blockIdx.y;
    const float* s = (seg == 0) ? s0 : (seg == 1) ? s1 : (seg == 2) ? s2 : s3;
    u16* d = dst + (size_t)seg * 1048576;
    size_t i = (size_t)blockIdx.x * 256 + threadIdx.x;   // float4 index, 262,144 total
    float4 v = ((const float4*)s)[i];
    ushort4 o;
    o.x = f2bf(v.x); o.y = f2bf(v.y); o.z = f2bf(v.z); o.w = f2bf(v.w);
    ((ushort4*)d)[i] = o;
}

// ---------------------------------------------------------------------------
// Kernel 1: Y = X @ W^T  (X [4096,1024], W [1024,1024], bf16 row-major in ws).
// grid.z selects (q,k,v). Output written to ws in [B,H,T,DK] layout, bf16.
// ---------------------------------------------------------------------------
__global__ __launch_bounds__(256) void proj_qkv(
    const u16* __restrict__ Xq, const u16* __restrict__ Xk, const u16* __restrict__ Xv,
    const u16* __restrict__ Wq, const u16* __restrict__ Wk, const u16* __restrict__ Wv,
    u16* __restrict__ Qb, u16* __restrict__ Kb, u16* __restrict__ Vb)
{
    int z = blockIdx.z;
    const u16* X = (z == 0) ? Xq : (z == 1) ? Xk : Xv;
    const u16* W = (z == 0) ? Wq : (z == 1) ? Wk : Wv;
    u16*       Y = (z == 0) ? Qb : (z == 1) ? Kb : Vb;

    const int lane = threadIdx.x & 63;
    const int wave = threadIdx.x >> 6;
    const int c    = lane & 15;      // A/B row within tile
    const int quad = lane >> 4;      // k-subchunk selector

    const int m0 = blockIdx.y * 64 + wave * 16;
    const int n0 = blockIdx.x * 64;

    const u16* arow  = X + (size_t)(m0 + c) * D_ + quad * 8;
    const u16* brow0 = W + (size_t)(n0 + c) * D_ + quad * 8;

    f4v acc[4] = {};
    for (int k0 = 0; k0 < D_; k0 += 32) {
        s8v a = *(const s8v*)(arow + k0);
#pragma unroll
        for (int j = 0; j < 4; ++j) {
            s8v b = *(const s8v*)(brow0 + (size_t)j * 16 * D_ + k0);
            acc[j] = __builtin_amdgcn_mfma_f32_16x16x32_bf16(a, b, acc[j], 0, 0, 0);
        }
    }
    // C/D layout: col = lane&15, row = quad*4 + r
#pragma unroll
    for (int j = 0; j < 4; ++j) {
#pragma unroll
        for (int r = 0; r < 4; ++r) {
            int m = m0 + quad * 4 + r;          // global token row
            int e = n0 + j * 16 + c;            // output feature
            int bb = m >> 11, t = m & (T_ - 1);
            int h = e >> 6,  d = e & 63;
            Y[((size_t)(bb * H_ + h) * T_ + t) * DK_ + d] = f2bf(acc[j][r]);
        }
    }
}

// ---------------------------------------------------------------------------
// Kernel 2: attention for one (b,h) and a 16-query tile per block. 4 waves.
// Pass 1: online softmax stats (m,l); pass 2: recompute S, write fp32 weights,
// PV via MFMA (P round-trips LDS for C->A layout change).
// ---------------------------------------------------------------------------
__global__ __launch_bounds__(256) void attn_kernel(
    const u16* __restrict__ Qb, const u16* __restrict__ Kb, const u16* __restrict__ Vb,
    float* __restrict__ weights, u16* __restrict__ ctx)
{
    const int bh = blockIdx.y;           // b*H + h, 0..31
    const int q0 = blockIdx.x * 16;      // query tile base
    const int lane = threadIdx.x & 63;
    const int wave = threadIdx.x >> 6;
    const int c    = lane & 15;
    const int quad = lane >> 4;

    const u16* Qh = Qb + (size_t)bh * T_ * DK_;
    const u16* Kh = Kb + (size_t)bh * T_ * DK_;
    const u16* Vh = Vb + (size_t)bh * T_ * DK_;

    __shared__ __attribute__((aligned(16))) u16  qs[16 * DK_];   // Q tile [16][64]
    __shared__ __attribute__((aligned(16))) u16  pbuf[16][64];   // P chunk, bf16
    __shared__ float wm[4][16], wl[4][16];
    __shared__ float rowM[16], rowInv[16];

    // stage Q tile (rows q0..q0+15 contiguous in [T,DK])
    {
        const s8v* src = (const s8v*)(Qh + (size_t)q0 * DK_);
        s8v* dst = (s8v*)qs;
        for (int i = threadIdx.x; i < 16 * DK_ / 8; i += 256) dst[i] = src[i];
    }
    __syncthreads();

    // A-fragments from Q tile: A[m = lane&15][k = quad*8 + j]
    s8v aq0 = *(const s8v*)(&qs[c * DK_ + quad * 8]);
    s8v aq1 = *(const s8v*)(&qs[c * DK_ + 32 + quad * 8]);

    // ---- pass 1: online (m, l) ----
    float m_run[4], l_run[4];
#pragma unroll
    for (int r = 0; r < 4; ++r) { m_run[r] = -1e30f; l_run[r] = 0.f; }

    for (int kt = wave; kt < T_ / 16; kt += 4) {
        const u16* krow = Kh + (size_t)(kt * 16 + c) * DK_ + quad * 8;
        s8v b0 = *(const s8v*)(krow);
        s8v b1 = *(const s8v*)(krow + 32);
        f4v s = {};
        s = __builtin_amdgcn_mfma_f32_16x16x32_bf16(aq0, b0, s, 0, 0, 0);
        s = __builtin_amdgcn_mfma_f32_16x16x32_bf16(aq1, b1, s, 0, 0, 0);
#pragma unroll
        for (int r = 0; r < 4; ++r) {
            float v = s[r] * 0.125f;     // 1/sqrt(64)
            float tm = v;
#pragma unroll
            for (int off = 1; off < 16; off <<= 1) tm = fmaxf(tm, __shfl_xor(tm, off));
            float mn = fmaxf(m_run[r], tm);
            float p = __expf(v - mn);
            float ts = p;
#pragma unroll
            for (int off = 1; off < 16; off <<= 1) ts += __shfl_xor(ts, off);
            l_run[r] = l_run[r] * __expf(m_run[r] - mn) + ts;
            m_run[r] = mn;
        }
    }
    if (c == 0) {
#pragma unroll
        for (int r = 0; r < 4; ++r) { wm[wave][quad * 4 + r] = m_run[r]; wl[wave][quad * 4 + r] = l_run[r]; }
    }
    __syncthreads();
    if (threadIdx.x < 16) {
        int row = threadIdx.x;
        float M = -1e30f;
#pragma unroll
        for (int w = 0; w < 4; ++w) M = fmaxf(M, wm[w][row]);
        float L = 0.f;
#pragma unroll
        for (int w = 0; w < 4; ++w) L += wl[w][row] * __expf(wm[w][row] - M);
        rowM[row] = M; rowInv[row] = 1.0f / L;
    }
    __syncthreads();

    // ---- pass 2: recompute S, emit fp32 weights, accumulate PV ----
    f4v oacc = {};                       // this wave's 16-dim slab
    for (int c64 = 0; c64 < T_ / 64; ++c64) {
        int kt = c64 * 4 + wave;
        const u16* krow = Kh + (size_t)(kt * 16 + c) * DK_ + quad * 8;
        s8v b0 = *(const s8v*)(krow);
        s8v b1 = *(const s8v*)(krow + 32);
        f4v s = {};
        s = __builtin_amdgcn_mfma_f32_16x16x32_bf16(aq0, b0, s, 0, 0, 0);
        s = __builtin_amdgcn_mfma_f32_16x16x32_bf16(aq1, b1, s, 0, 0, 0);
#pragma unroll
        for (int r = 0; r < 4; ++r) {
            int row = quad * 4 + r;
            float p = __expf(s[r] * 0.125f - rowM[row]) * rowInv[row];
            pbuf[row][wave * 16 + c] = f2bf(p);
            weights[((size_t)(bh * T_ + q0 + row)) * T_ + kt * 16 + c] = p;
        }
        __syncthreads();
        // PV over this 64-key chunk; A = P (C->A layout via pbuf), B = V slice
        int key0 = c64 * 64;
#pragma unroll
        for (int kk = 0; kk < 64; kk += 32) {
            s8v af = *(const s8v*)(&pbuf[c][kk + quad * 8]);
            s8v bv;
#pragma unroll
            for (int j = 0; j < 8; ++j)
                bv[j] = (short)Vh[(size_t)(key0 + kk + quad * 8 + j) * DK_ + wave * 16 + c];
            oacc = __builtin_amdgcn_mfma_f32_16x16x32_bf16(af, bv, oacc, 0, 0, 0);
        }
        __syncthreads();
    }

    // write context bf16 in [B,T,D] (input to out-projection)
    const int bb = bh >> 4, h = bh & 15;
#pragma unroll
    for (int r = 0; r < 4; ++r) {
        int row = q0 + quad * 4 + r;
        int col = h * 64 + wave * 16 + c;
        ctx[((size_t)(bb * T_ + row)) * D_ + col] = f2bf(oacc[r]);
    }
}

// ---------------------------------------------------------------------------
// Kernel 3: out = ctx @ W_o^T -> fp32 into d_out region 0.
// ---------------------------------------------------------------------------
__global__ __launch_bounds__(256) void out_proj(
    const u16* __restrict__ X, const u16* __restrict__ W, float* __restrict__ Y)
{
    const int lane = threadIdx.x & 63;
    const int wave = threadIdx.x >> 6;
    const int c    = lane & 15;
    const int quad = lane >> 4;

    const int m0 = blockIdx.y * 64 + wave * 16;
    const int n0 = blockIdx.x * 64;

    const u16* arow  = X + (size_t)(m0 + c) * D_ + quad * 8;
    const u16* brow0 = W + (size_t)(n0 + c) * D_ + quad * 8;

    f4v acc[4] = {};
    for (int k0 = 0; k0 < D_; k0 += 32) {
        s8v a = *(const s8v*)(arow + k0);
#pragma unroll
        for (int j = 0; j < 4; ++j) {
            s8v b = *(const s8v*)(brow0 + (size_t)j * 16 * D_ + k0);
            acc[j] = __builtin_amdgcn_mfma_f32_16x16x32_bf16(a, b, acc[j], 0, 0, 0);
        }
    }
#pragma unroll
    for (int j = 0; j < 4; ++j) {
#pragma unroll
        for (int r = 0; r < 4; ++r) {
            int m = m0 + quad * 4 + r;
            int e = n0 + j * 16 + c;
            Y[(size_t)m * D_ + e] = acc[j][r];
        }
    }
}

extern "C" void kernel_launch(void* const* d_in, const int* in_sizes, int n_in,
                              void* d_out, int out_size, void* d_ws, size_t ws_size,
                              hipStream_t stream) {
    const float* query = (const float*)d_in[0];
    const float* key_  = (const float*)d_in[1];
    const float* value = (const float*)d_in[2];
    const float* W_q   = (const float*)d_in[3];
    const float* W_k   = (const float*)d_in[4];
    const float* W_v   = (const float*)d_in[5];
    const float* W_o   = (const float*)d_in[6];

    float* out_attn = (float*)d_out;                               // [B,T,D] fp32
    float* weights  = (float*)d_out + (size_t)B_ * T_ * D_;        // [B,H,T,T] fp32

    // ws layout (all bf16): Xq,Xk,Xv | Wq,Wk,Wv,Wo | Qb,Kb,Vb | ctx  = 64 MB
    const size_t perX = (size_t)M_ * D_;      // 4,194,304
    const size_t perW = (size_t)D_ * D_;      // 1,048,576
    u16* Xb  = (u16*)d_ws;                    // 3 segments
    u16* Wb  = Xb + 3 * perX;                 // 4 segments
    u16* Qb  = Wb + 4 * perW;
    u16* Kb  = Qb + perX;
    u16* Vb  = Kb + perX;
    u16* ctx = Vb + perX;

    dim3 gA(4096, 3, 1);
    cvtA<<<gA, 256, 0, stream>>>(query, key_, value, Xb);
    dim3 gB(1024, 4, 1);
    cvtB<<<gB, 256, 0, stream>>>(W_q, W_k, W_v, W_o, Wb);

    dim3 gproj(D_ / 64, M_ / 64, 3);
    proj_qkv<<<gproj, 256, 0, stream>>>(Xb, Xb + perX, Xb + 2 * perX,
                                        Wb, Wb + perW, Wb + 2 * perW,
                                        Qb, Kb, Vb);

    dim3 gattn(T_ / 16, B_ * H_, 1);
    attn_kernel<<<gattn, 256, 0, stream>>>(Qb, Kb, Vb, weights, ctx);

    dim3 gout(D_ / 64, M_ / 64, 1);
    out_proj<<<gout, 256, 0, stream>>>(ctx, Wb + 3 * perW, out_attn);
}